// Round 3
// baseline (169.951 us; speedup 1.0000x reference)
//
#include <hip/hip_runtime.h>

// Length regulator: out[b, p, :] = att_out[b, idx(b,p), :] for p < total[b], else 0.
// Two-kernel structure:
//   K1 (32 blocks): per-batch scan + searchsorted -> idx map in d_ws (-1 = masked).
//   K2 (4096 blocks): barrier-free gather/stream copy using the precomputed map.

constexpr int B = 32;
constexpr int L = 256;
constexpr int D = 512;
constexpr int MAX_LEN = 2048;
constexpr int POS_PER_BLOCK = 16;   // output positions per copy block
constexpr int THREADS = 256;

// native clang vector (HIP float4 is a class -> rejected by nontemporal builtin)
typedef float vfloat4 __attribute__((ext_vector_type(4)));

// ---------------- Kernel 1: index map ----------------
__global__ __launch_bounds__(THREADS) void index_kernel(
    const float* __restrict__ duration,  // (B, L)
    const int*   __restrict__ alpha_p,   // scalar
    int*         __restrict__ idx_map)   // (B, MAX_LEN)
{
    __shared__ int csum[L];
    const int b   = blockIdx.x;
    const int tid = threadIdx.x;
    const float alpha = (float)alpha_p[0];

    // round-half-to-even matches jnp.round
    int v = (int)rintf(duration[b * L + tid] * alpha);
    csum[tid] = v;
    __syncthreads();
    #pragma unroll
    for (int off = 1; off < L; off <<= 1) {
        int add = (tid >= off) ? csum[tid - off] : 0;
        __syncthreads();
        csum[tid] += add;
        __syncthreads();
    }
    const int total = csum[L - 1];

    // each thread resolves 8 positions
    #pragma unroll
    for (int j = 0; j < MAX_LEN / THREADS; ++j) {
        const int p = tid + j * THREADS;
        int result = -1;
        if (p < total) {
            int lo = 0, hi = L;   // upper_bound: first idx with csum[idx] > p
            while (lo < hi) {
                int mid = (lo + hi) >> 1;
                if (csum[mid] <= p) lo = mid + 1; else hi = mid;
            }
            result = lo;   // p < total => lo <= L-1, clamp unnecessary
        }
        idx_map[b * MAX_LEN + p] = result;
    }
}

// ---------------- Kernel 2: streaming gather copy ----------------
__global__ __launch_bounds__(THREADS) void copy_kernel(
    const float* __restrict__ att_out,   // (B, L, D)
    const int*   __restrict__ idx_map,   // (B, MAX_LEN)
    float*       __restrict__ out)       // (B, MAX_LEN, D)
{
    const int b        = blockIdx.y;
    const int pos_base = blockIdx.x * POS_PER_BLOCK;
    const int tid      = threadIdx.x;
    const int lane     = tid & 127;      // 128 float4 lanes per row
    const int row      = tid >> 7;       // 0 or 1 (wave-aligned: waves 0,1 -> row 0)

    const vfloat4* __restrict__ src4 = (const vfloat4*)(att_out + (size_t)b * L * D);
    vfloat4*       __restrict__ dst4 = (vfloat4*)(out + (size_t)b * MAX_LEN * D);
    const int*     __restrict__ im   = idx_map + b * MAX_LEN + pos_base;

    // load all indices up-front: 8 independent loads, full ILP
    int ids[POS_PER_BLOCK / 2];
    #pragma unroll
    for (int i = 0; i < POS_PER_BLOCK / 2; ++i)
        ids[i] = im[2 * i + row];

    #pragma unroll
    for (int i = 0; i < POS_PER_BLOCK / 2; ++i) {
        const int p  = pos_base + 2 * i + row;
        const int id = ids[i];
        vfloat4 v = (vfloat4)0.f;
        if (id >= 0)
            v = src4[(size_t)id * (D / 4) + lane];
        // output is write-once, never re-read: bypass cache pollution
        __builtin_nontemporal_store(v, &dst4[(size_t)p * (D / 4) + lane]);
    }
}

extern "C" void kernel_launch(void* const* d_in, const int* in_sizes, int n_in,
                              void* d_out, int out_size, void* d_ws, size_t ws_size,
                              hipStream_t stream) {
    const float* att_out  = (const float*)d_in[0];
    const float* duration = (const float*)d_in[1];
    const int*   alpha    = (const int*)d_in[2];
    float*       out      = (float*)d_out;
    int*         idx_map  = (int*)d_ws;   // B*MAX_LEN ints = 256 KB

    index_kernel<<<dim3(B), dim3(THREADS), 0, stream>>>(duration, alpha, idx_map);

    dim3 grid(MAX_LEN / POS_PER_BLOCK, B);   // (128, 32) = 4096 blocks
    copy_kernel<<<grid, dim3(THREADS), 0, stream>>>(att_out, idx_map, out);
}

// Round 4
// 164.873 us; speedup vs baseline: 1.0308x; 1.0308x over previous
//
#include <hip/hip_runtime.h>

// Length regulator: out[b, p, :] = att_out[b, idx(b,p), :] for p < total[b], else 0.
// Two-kernel structure:
//   K1 (32 blocks): per-batch scan + searchsorted -> idx map in d_ws (-1 = masked).
//   K2 (2048 blocks): barrier-free gather/stream copy, full occupancy (8 blk/CU).

constexpr int B = 32;
constexpr int L = 256;
constexpr int D = 512;
constexpr int MAX_LEN = 2048;
constexpr int POS_PER_BLOCK = 32;   // output positions per copy block (64 KB/block)
constexpr int THREADS = 256;

typedef float vfloat4 __attribute__((ext_vector_type(4)));

// ---------------- Kernel 1: index map ----------------
__global__ __launch_bounds__(THREADS) void index_kernel(
    const float* __restrict__ duration,  // (B, L)
    const int*   __restrict__ alpha_p,   // scalar
    int*         __restrict__ idx_map)   // (B, MAX_LEN)
{
    __shared__ int csum[L];
    const int b   = blockIdx.x;
    const int tid = threadIdx.x;
    const float alpha = (float)alpha_p[0];

    // round-half-to-even matches jnp.round
    int v = (int)rintf(duration[b * L + tid] * alpha);
    csum[tid] = v;
    __syncthreads();
    #pragma unroll
    for (int off = 1; off < L; off <<= 1) {
        int add = (tid >= off) ? csum[tid - off] : 0;
        __syncthreads();
        csum[tid] += add;
        __syncthreads();
    }
    const int total = csum[L - 1];

    // each thread resolves 8 positions
    #pragma unroll
    for (int j = 0; j < MAX_LEN / THREADS; ++j) {
        const int p = tid + j * THREADS;
        int result = -1;
        if (p < total) {
            int lo = 0, hi = L;   // upper_bound: first idx with csum[idx] > p
            while (lo < hi) {
                int mid = (lo + hi) >> 1;
                if (csum[mid] <= p) lo = mid + 1; else hi = mid;
            }
            result = lo;   // p < total => lo <= L-1
        }
        idx_map[b * MAX_LEN + p] = result;
    }
}

// ---------------- Kernel 2: streaming gather copy ----------------
__global__ __launch_bounds__(THREADS) void copy_kernel(
    const float* __restrict__ att_out,   // (B, L, D)
    const int*   __restrict__ idx_map,   // (B, MAX_LEN)
    float*       __restrict__ out)       // (B, MAX_LEN, D)
{
    const int b        = blockIdx.y;
    const int pos_base = blockIdx.x * POS_PER_BLOCK;
    const int tid      = threadIdx.x;
    const int lane     = tid & 127;      // 128 float4 lanes per row
    const int row      = tid >> 7;       // uniform per wave (waves 0,1 -> 0; 2,3 -> 1)

    const vfloat4* __restrict__ src4 = (const vfloat4*)(att_out + (size_t)b * L * D);
    vfloat4*       __restrict__ dst4 = (vfloat4*)(out + (size_t)b * MAX_LEN * D);
    const int*     __restrict__ im   = idx_map + b * MAX_LEN + pos_base;

    // prefetch all indices: wave-uniform addresses -> broadcast loads, full ILP
    int ids[POS_PER_BLOCK / 2];
    #pragma unroll
    for (int i = 0; i < POS_PER_BLOCK / 2; ++i)
        ids[i] = im[2 * i + row];

    #pragma unroll
    for (int i = 0; i < POS_PER_BLOCK / 2; ++i) {
        const int p  = pos_base + 2 * i + row;
        const int id = ids[i];
        vfloat4 v = (vfloat4)0.f;
        if (id >= 0)
            v = src4[(size_t)id * (D / 4) + lane];
        dst4[(size_t)p * (D / 4) + lane] = v;   // plain store: proven 6+ TB/s path
    }
}

extern "C" void kernel_launch(void* const* d_in, const int* in_sizes, int n_in,
                              void* d_out, int out_size, void* d_ws, size_t ws_size,
                              hipStream_t stream) {
    const float* att_out  = (const float*)d_in[0];
    const float* duration = (const float*)d_in[1];
    const int*   alpha    = (const int*)d_in[2];
    float*       out      = (float*)d_out;
    int*         idx_map  = (int*)d_ws;   // B*MAX_LEN ints = 256 KB

    index_kernel<<<dim3(B), dim3(THREADS), 0, stream>>>(duration, alpha, idx_map);

    dim3 grid(MAX_LEN / POS_PER_BLOCK, B);   // (64, 32) = 2048 blocks -> 8/CU resident
    copy_kernel<<<grid, dim3(THREADS), 0, stream>>>(att_out, idx_map, out);
}

// Round 6
// 161.226 us; speedup vs baseline: 1.0541x; 1.0226x over previous
//
#include <hip/hip_runtime.h>

// Length regulator: out[b, p, :] = att_out[b, idx(b,p), :] for p < total[b], else 0.
// Fused single kernel. Per block: wave-0 shuffle-scan of round(duration*alpha)
// -> csum in LDS (1 barrier), hoisted branchless searches, streaming gather copy.

constexpr int B = 32;
constexpr int L = 256;
constexpr int D = 512;
constexpr int MAX_LEN = 2048;
constexpr int POS_PER_BLOCK = 32;   // 2048 blocks = 8 blocks/CU resident, no turnover
constexpr int THREADS = 256;
constexpr int ITERS = POS_PER_BLOCK / 2;   // 2 rows in flight per iteration

typedef float vfloat4 __attribute__((ext_vector_type(4)));

__global__ __launch_bounds__(THREADS) void length_regulator_kernel(
    const float* __restrict__ att_out,   // (B, L, D)
    const float* __restrict__ duration,  // (B, L)
    const int*   __restrict__ alpha_p,   // scalar
    float*       __restrict__ out)       // (B, MAX_LEN, D)
{
    __shared__ int csum[L];

    const int b        = blockIdx.y;
    const int pos_base = blockIdx.x * POS_PER_BLOCK;
    const int tid      = threadIdx.x;

    // ---- prologue: wave 0 only, 6-step shuffle scan, one LDS write ----
    if (tid < 64) {
        const float alpha = (float)alpha_p[0];
        vfloat4 d4 = ((const vfloat4*)(duration + b * L))[tid];   // 4 durations/lane
        // round-half-to-even matches jnp.round
        int r0 = (int)rintf(d4.x * alpha);
        int r1 = (int)rintf(d4.y * alpha);
        int r2 = (int)rintf(d4.z * alpha);
        int r3 = (int)rintf(d4.w * alpha);
        int s  = r0 + r1 + r2 + r3;
        int sc = s;                         // inclusive scan of per-lane sums
        #pragma unroll
        for (int off = 1; off < 64; off <<= 1) {
            int n = __shfl_up(sc, off, 64);
            if (tid >= off) sc += n;
        }
        const int base = sc - s;            // exclusive prefix
        csum[4 * tid + 0] = base + r0;
        csum[4 * tid + 1] = base + r0 + r1;
        csum[4 * tid + 2] = base + r0 + r1 + r2;
        csum[4 * tid + 3] = sc;
    }
    __syncthreads();                        // the ONLY barrier

    const int total = csum[L - 1];          // broadcast read
    const int lane  = tid & 127;            // 128 float4 lanes per row
    const int row   = tid >> 7;             // wave-uniform (waves 0,1 -> 0; 2,3 -> 1)

    // ---- hoisted searches: branchless uniform upper_bound, exactly 8 steps ----
    // idx = #elements <= p  (== searchsorted side='right'); exact for size 256.
    int ids[ITERS];
    #pragma unroll
    for (int i = 0; i < ITERS; ++i) {
        const int p = pos_base + 2 * i + row;
        int idx = 0;
        #pragma unroll
        for (int w = 128; w >= 1; w >>= 1)
            idx += (csum[idx + w - 1] <= p) ? w : 0;
        ids[i] = (p < total) ? idx : -1;    // p < total => idx <= L-1
    }

    // ---- barrier-free streaming gather copy: 64 KB per block ----
    const vfloat4* __restrict__ src4 = (const vfloat4*)(att_out + (size_t)b * L * D);
    vfloat4*       __restrict__ dst4 = (vfloat4*)(out + (size_t)b * MAX_LEN * D);

    #pragma unroll
    for (int i = 0; i < ITERS; ++i) {
        const int p  = pos_base + 2 * i + row;
        const int id = ids[i];
        vfloat4 v = (vfloat4)0.f;
        if (id >= 0)
            v = src4[(size_t)id * (D / 4) + lane];
        dst4[(size_t)p * (D / 4) + lane] = v;
    }
}

extern "C" void kernel_launch(void* const* d_in, const int* in_sizes, int n_in,
                              void* d_out, int out_size, void* d_ws, size_t ws_size,
                              hipStream_t stream) {
    const float* att_out  = (const float*)d_in[0];
    const float* duration = (const float*)d_in[1];
    const int*   alpha    = (const int*)d_in[2];
    float*       out      = (float*)d_out;

    dim3 grid(MAX_LEN / POS_PER_BLOCK, B);   // (64, 32) = 2048 blocks
    length_regulator_kernel<<<grid, dim3(THREADS), 0, stream>>>(att_out, duration, alpha, out);
}